// Round 6
// baseline (430.515 us; speedup 1.0000x reference)
//
#include <hip/hip_runtime.h>

#define NN 4
#define CC 256
#define HH 128
#define FWBv 16
#define BLK 8
#define NBBOX 100
#define MM (NBBOX * NN * FWBv * FWBv)  // 102400

typedef __attribute__((ext_vector_type(8))) short bf16x8;
typedef __attribute__((ext_vector_type(4))) float f32x4;

__device__ __forceinline__ unsigned short f2bf(float x) {
  union { float f; unsigned int u; } v; v.f = x;
  unsigned int r = v.u + 0x7FFFu + ((v.u >> 16) & 1u);
  return (unsigned short)(r >> 16);
}

__device__ __forceinline__ float bfbits2f(unsigned int hi16) {
  union { float f; unsigned int u; } v; v.u = hi16;
  return v.f;
}

__device__ __forceinline__ unsigned int pk(float a, float b) {
  return (unsigned int)f2bf(a) | ((unsigned int)f2bf(b) << 16);
}

// ---------------- Kernel 0: weight fp32 -> bf16, FRAGMENT-MAJOR ----------------
// Wf/Ww: fragment f = (kc*16 + g)*64 + lane  (kc<8, g<16, lane<64)
//   holds W[g*16 + (lane&15)][kc*32 + (lane>>4)*8 + j], j=0..7  (16B per lane)
// Wpw:   fragment f = (kc*4 + g)*64 + lane   (kc<8, g<4)
__global__ __launch_bounds__(256) void k_convert(
    const float* __restrict__ Wf, const float* __restrict__ Ww,
    const float* __restrict__ Wpw,
    unsigned short* __restrict__ oWf, unsigned short* __restrict__ oWw,
    unsigned short* __restrict__ oWpw) {
  const int i = blockIdx.x * 256 + threadIdx.x;  // grid = 40 blocks -> i < 10240
  if (i < 8192) {
    const int lane = i & 63, g = (i >> 6) & 15, kc = i >> 10;
    const int row = g * 16 + (lane & 15);
    const int col0 = kc * 32 + (lane >> 4) * 8;
    {
      const float* s = Wf + (size_t)row * 256 + col0;
      const float4 a = *(const float4*)s, b = *(const float4*)(s + 4);
      *(uint4*)(oWf + (size_t)i * 8) =
          make_uint4(pk(a.x, a.y), pk(a.z, a.w), pk(b.x, b.y), pk(b.z, b.w));
    }
    {
      const float* s = Ww + (size_t)row * 256 + col0;
      const float4 a = *(const float4*)s, b = *(const float4*)(s + 4);
      *(uint4*)(oWw + (size_t)i * 8) =
          make_uint4(pk(a.x, a.y), pk(a.z, a.w), pk(b.x, b.y), pk(b.z, b.w));
    }
  } else {
    const int j = i - 8192;  // [0, 2048)
    const int lane = j & 63, g = (j >> 6) & 3, kc = j >> 8;
    const int row = g * 16 + (lane & 15);
    const int col0 = kc * 32 + (lane >> 4) * 8;
    const float* s = Wpw + (size_t)row * 256 + col0;
    const float4 a = *(const float4*)s, b = *(const float4*)(s + 4);
    *(uint4*)(oWpw + (size_t)j * 8) =
        make_uint4(pk(a.x, a.y), pk(a.z, a.w), pk(b.x, b.y), pk(b.z, b.w));
  }
}

// fragment load: one coalesced 1KB global_load_dwordx4 per wave
__device__ __forceinline__ bf16x8 ld_frag(const unsigned short* __restrict__ W,
                                          int frag, int lane) {
  return *(const bf16x8*)(W + (((size_t)frag * 64 + lane) << 3));
}

// One BK=32 compute step: weights already in regs; 4 ds_read (xs) + 16 MFMA.
__device__ __forceinline__ void bodyR(const bf16x8 aw[4],
                                      const unsigned short (*xsp)[264],
                                      int kcol, int lr, f32x4 acc[4][4]) {
  bf16x8 bx[4];
#pragma unroll
  for (int mt = 0; mt < 4; ++mt)
    bx[mt] = *(const bf16x8*)&xsp[mt * 16 + lr][kcol];
  __builtin_amdgcn_s_setprio(1);
#pragma unroll
  for (int mt = 0; mt < 4; ++mt)
#pragma unroll
    for (int nt = 0; nt < 4; ++nt)
      acc[mt][nt] = __builtin_amdgcn_mfma_f32_16x16x32_bf16(
          aw[nt], bx[mt], acc[mt][nt], 0, 0, 0);
  __builtin_amdgcn_s_setprio(0);
}

// ---------------- Kernel 1: feat_f, feat_w, point_weight ----------------
// R6: ZONE-SAFE scratch layout per 1KB out_slot row (so k2's c-half blocks
// never read outside their own write zone):
//   bytes [  0,128): pw bf16[64]            (zone 0 copy)
//   bytes [128,384): feat_f bf16 c=0..127   (zone 0)
//   bytes [512,640): pw bf16[64]            (zone 1 copy)
//   bytes [640,896): feat_f bf16 c=128..255 (zone 1)
// ushort idx: pw j -> j and 256+j; feat_f c -> 64+c (c<128), 192+c (c>=128).
__global__ __launch_bounds__(256, 3) void k1(
    const float* __restrict__ rois,
    const unsigned short* __restrict__ Wf,   // bf16 fragment-major [8192][8]
    const unsigned short* __restrict__ Ww,   // bf16 fragment-major [8192][8]
    const unsigned short* __restrict__ Wpw,  // bf16 fragment-major [2048][8]
    const float* __restrict__ bf_, const float* __restrict__ bw_,
    const float* __restrict__ bpw_,
    float* __restrict__ out_slot)
{
  __shared__ __align__(16) unsigned short xs[64][264];  // 33.8 KB, only LDS
  unsigned short* os = (unsigned short*)out_slot;
  const int t = threadIdx.x;
  const int lane = t & 63, w = t >> 6;
  const int lr = lane & 15, quad = lane >> 4;
  const int row_base = blockIdx.x * 64;
  const int w4 = w * 4;
  const int zbase = (w < 2) ? 64 : 192;  // feat_f ushort base for this wave's cols

  // preload pass-A chunk 0 weights (in flight during the X stage)
  bf16x8 aw[2][4];
#pragma unroll
  for (int nt = 0; nt < 4; ++nt) aw[0][nt] = ld_frag(Wf, w4 + nt, lane);

  // stage X: 64x256 fp32 -> bf16 LDS (coalesced float4 loads)
#pragma unroll
  for (int i = 0; i < 16; ++i) {
    const int elem = (i * 256 + t) * 4;
    const int r = elem >> 8, c = elem & 255;
    const float4 v = *(const float4*)(rois + (size_t)row_base * 256 + elem);
    *(uint2*)&xs[r][c] = make_uint2(pk(v.x, v.y), pk(v.z, v.w));
  }
  asm volatile("s_waitcnt lgkmcnt(0)" ::: "memory");
  __builtin_amdgcn_s_barrier();  // xs visible to all waves

  f32x4 acc[4][4];
#pragma unroll
  for (int mt = 0; mt < 4; ++mt)
#pragma unroll
    for (int nt = 0; nt < 4; ++nt) acc[mt][nt] = (f32x4){0.f, 0.f, 0.f, 0.f};

  // ---- pass A: feat_f = relu(x @ Wf^T + bf) ----
#pragma unroll
  for (int kc = 0; kc < 8; ++kc) {
    const unsigned short* nsrc = (kc < 7) ? Wf : Ww;  // tail prefetches pass B
    const int nkc = (kc < 7) ? kc + 1 : 0;
#pragma unroll
    for (int nt = 0; nt < 4; ++nt)
      aw[(kc + 1) & 1][nt] = ld_frag(nsrc, nkc * 16 + w4 + nt, lane);
    bodyR(aw[kc & 1], xs, kc * 32 + quad * 8, lr, acc);
  }

  // epilogue A: feat_f = relu(acc+bias) -> bf16, zone-split layout
#pragma unroll
  for (int nt = 0; nt < 4; ++nt) {
    const int col0 = w * 64 + nt * 16 + quad * 4;
    const float4 b4 = *(const float4*)(bf_ + col0);
#pragma unroll
    for (int mt = 0; mt < 4; ++mt) {
      float v0 = acc[mt][nt][0] + b4.x; v0 = v0 > 0.f ? v0 : 0.f;
      float v1 = acc[mt][nt][1] + b4.y; v1 = v1 > 0.f ? v1 : 0.f;
      float v2 = acc[mt][nt][2] + b4.z; v2 = v2 > 0.f ? v2 : 0.f;
      float v3 = acc[mt][nt][3] + b4.w; v3 = v3 > 0.f ? v3 : 0.f;
      *(uint2*)&os[(size_t)(row_base + mt * 16 + lr) * 512 + zbase + col0] =
          make_uint2(pk(v0, v1), pk(v2, v3));
      acc[mt][nt] = (f32x4){0.f, 0.f, 0.f, 0.f};  // reset for pass B
    }
  }

  // ---- pass B: feat_w = relu(x @ Ww^T + bw) ----
#pragma unroll
  for (int kc = 0; kc < 8; ++kc) {
    if (kc < 7) {
#pragma unroll
      for (int nt = 0; nt < 4; ++nt)
        aw[(kc + 1) & 1][nt] = ld_frag(Ww, (kc + 1) * 16 + w4 + nt, lane);
    }
    bodyR(aw[kc & 1], xs, kc * 32 + quad * 8, lr, acc);
  }

  // prefetch ALL pass-C weights to regs (8KB/wave from L2, hides under epiB)
  bf16x8 apw[8];
#pragma unroll
  for (int idx = 0; idx < 8; ++idx)
    apw[idx] = ld_frag(Wpw, idx * 4 + w, lane);

  __builtin_amdgcn_s_barrier();  // ALL waves done reading xs (pass B)

  // epilogue B: feat_w = relu(acc + bias) -> bf16 back into xs
#pragma unroll
  for (int nt = 0; nt < 4; ++nt) {
    const int col0 = w * 64 + nt * 16 + quad * 4;
    const float4 b4 = *(const float4*)(bw_ + col0);
#pragma unroll
    for (int mt = 0; mt < 4; ++mt) {
      float v0 = acc[mt][nt][0] + b4.x; v0 = v0 > 0.f ? v0 : 0.f;
      float v1 = acc[mt][nt][1] + b4.y; v1 = v1 > 0.f ? v1 : 0.f;
      float v2 = acc[mt][nt][2] + b4.z; v2 = v2 > 0.f ? v2 : 0.f;
      float v3 = acc[mt][nt][3] + b4.w; v3 = v3 > 0.f ? v3 : 0.f;
      *(uint2*)&xs[mt * 16 + lr][col0] = make_uint2(pk(v0, v1), pk(v2, v3));
    }
  }
  asm volatile("s_waitcnt lgkmcnt(0)" ::: "memory");
  __builtin_amdgcn_s_barrier();  // new xs (feat_w) visible

  // ---- pass C: pw = feat_w @ Wpw^T + bpw, wave w -> cols [w*16, w*16+16) ----
  f32x4 acc2[4];
#pragma unroll
  for (int mt = 0; mt < 4; ++mt) acc2[mt] = (f32x4){0.f, 0.f, 0.f, 0.f};
#pragma unroll
  for (int idx = 0; idx < 8; ++idx) {  // idx = c*2+kt
    const int kcol = idx * 32 + quad * 8;
    __builtin_amdgcn_s_setprio(1);
#pragma unroll
    for (int mt = 0; mt < 4; ++mt) {
      const bf16x8 bx = *(const bf16x8*)&xs[mt * 16 + lr][kcol];
      acc2[mt] =
          __builtin_amdgcn_mfma_f32_16x16x32_bf16(apw[idx], bx, acc2[mt], 0, 0, 0);
    }
    __builtin_amdgcn_s_setprio(0);
  }
  // epilogue C: pw bf16 into BOTH zone copies: ushort idx j0 and 256+j0
  {
    const int j0 = w * 16 + quad * 4;
    const float4 bj = *(const float4*)(bpw_ + j0);
#pragma unroll
    for (int mt = 0; mt < 4; ++mt) {
      const float v0 = acc2[mt][0] + bj.x, v1 = acc2[mt][1] + bj.y;
      const float v2 = acc2[mt][2] + bj.z, v3 = acc2[mt][3] + bj.w;
      const uint2 pv = make_uint2(pk(v0, v1), pk(v2, v3));
      const size_t rb = (size_t)(row_base + mt * 16 + lr) * 512;
      *(uint2*)&os[rb + j0] = pv;
      *(uint2*)&os[rb + 256 + j0] = pv;
    }
  }
}

// ---------------- Kernel 2: einsum + fused add ----------------
// R6: grid = 2048 half-blocks of 256 threads (4 waves); each handles one
// (n,p,q) x channel-half. Halves the per-block serial chain (stage 45KB,
// store 100KB) and gives 4 independent phase-offset chains per CU
// (LDS 34.5KB x4 = 138KB, VGPR<=128 via __launch_bounds__(256,4)).
// Logical id L = XCD-chunked(d); bid = L>>1, half = L&1 (the two halves of
// one bid stay on the same XCD -> shared pw/feature lines hit L2).
// Zone safety: half h reads pw/feat_f ONLY from bytes [h*512,(h+1)*512) of
// each row (k1's layout) and writes only that zone -> no cross-block race;
// in-block read-before-write ordered by the vmcnt(0)+barrier fence.
__global__ __launch_bounds__(256, 4) void k2(
    const float* __restrict__ feature,
    float* __restrict__ fused_slot,
    float* __restrict__ out_slot)
{
  __shared__ unsigned short fbuf[128][72];  // fb[c_local][j] bf16
  __shared__ unsigned short pwb[112][72];   // pw[k][j] bf16, rows 100..111 zero
  const int t = threadIdx.x;
  const int lane = t & 63, w = t >> 6;      // w 0..3
  const int lr = lane & 15, quad = lane >> 4;
  const int d = blockIdx.x;                 // 0..2047 hardware id
  const int L = ((d & 7) << 8) | (d >> 3);  // XCD-chunked logical id
  const int bid = L >> 1, half = L & 1;
  const int n = bid >> 8, p = (bid >> 4) & 15, q = bid & 15;
  const unsigned short* os = (const unsigned short*)out_slot;
  const int zf = 64 + (half << 8);          // feat_f ushort base in our zone

  // zero pad rows k=100..111 (432 uints over 256 threads)
  for (int z = t; z < 432; z += 256) {
    const int r = 100 + z / 36, cw = z % 36;
    *(unsigned int*)&pwb[r][cw * 2] = 0u;
  }

  // stage feature half: c = half*128 + c_local
  for (int pi = t; pi < 1024; pi += 256) {
    const int cl = pi >> 3, a = pi & 7;
    const int c = (half << 7) | cl;
    const float* fp =
        feature + (((size_t)n * 256 + c) * 128 + p * 8 + a) * 128 + q * 8;
    const float4 v0 = *(const float4*)fp;
    const float4 v1 = *(const float4*)(fp + 4);
    *(uint4*)&fbuf[cl][a * 8] =
        make_uint4(pk(v0.x, v0.y), pk(v0.z, v0.w), pk(v1.x, v1.y), pk(v1.z, v1.w));
  }

  // stage pw rows from OUR zone copy: ushort idx half*256 + ch*4
  for (int pi = t; pi < 1600; pi += 256) {
    const int k = pi >> 4, ch = pi & 15;
    const uint2 v = *(const uint2*)&os[(size_t)(bid + k * 1024) * 512 +
                                      (half << 8) + ch * 4];
    *(uint2*)&pwb[k][ch * 4] = v;
  }
  __syncthreads();

  // GEMM: mfma(fb_frag, pw_frag) -> D.row = channel, D.col = k
  f32x4 acc[7][2];
#pragma unroll
  for (int kt = 0; kt < 7; ++kt)
#pragma unroll
    for (int ct = 0; ct < 2; ++ct) acc[kt][ct] = (f32x4){0.f, 0.f, 0.f, 0.f};
#pragma unroll
  for (int kj = 0; kj < 2; ++kj) {
    const int kk = kj * 32 + quad * 8;
    bf16x8 fa[2];
#pragma unroll
    for (int ct = 0; ct < 2; ++ct)
      fa[ct] = *(const bf16x8*)&fbuf[w * 32 + ct * 16 + lr][kk];
    {  // half 1: kt 0..3
      bf16x8 pa[4];
#pragma unroll
      for (int kt = 0; kt < 4; ++kt)
        pa[kt] = *(const bf16x8*)&pwb[kt * 16 + lr][kk];
      __builtin_amdgcn_s_setprio(1);
#pragma unroll
      for (int kt = 0; kt < 4; ++kt)
#pragma unroll
        for (int ct = 0; ct < 2; ++ct)
          acc[kt][ct] = __builtin_amdgcn_mfma_f32_16x16x32_bf16(
              fa[ct], pa[kt], acc[kt][ct], 0, 0, 0);
      __builtin_amdgcn_s_setprio(0);
    }
    {  // half 2: kt 4..6
      bf16x8 pa[3];
#pragma unroll
      for (int kt = 0; kt < 3; ++kt)
        pa[kt] = *(const bf16x8*)&pwb[(kt + 4) * 16 + lr][kk];
      __builtin_amdgcn_s_setprio(1);
#pragma unroll
      for (int kt = 0; kt < 3; ++kt)
#pragma unroll
        for (int ct = 0; ct < 2; ++ct)
          acc[kt + 4][ct] = __builtin_amdgcn_mfma_f32_16x16x32_bf16(
              fa[ct], pa[kt], acc[kt + 4][ct], 0, 0, 0);
      __builtin_amdgcn_s_setprio(0);
    }
  }

  // feat_f bf16 prefetch from OUR zone (after GEMM: caps VGPR pressure)
  uint2 ffp[7][2];
#pragma unroll
  for (int kt = 0; kt < 7; ++kt) {
    const int k = kt * 16 + lr;
    if (k < 100) {
      const size_t ro = (size_t)(bid + k * 1024) * 512;
#pragma unroll
      for (int ct = 0; ct < 2; ++ct) {
        const int c0l = w * 32 + ct * 16 + quad * 4;  // local col 0..127
        ffp[kt][ct] = *(const uint2*)&os[ro + zf + c0l];
      }
    }
  }

  // fence: all reads of our zone complete before any overwrite
  asm volatile("s_waitcnt vmcnt(0)" ::: "memory");
  __builtin_amdgcn_s_barrier();

  // epilogue: float4 stores; k = kt*16+lr, global cols half*128 + c0l..+3
#pragma unroll
  for (int kt = 0; kt < 7; ++kt) {
    const int k = kt * 16 + lr;
    if (k < 100) {
      const size_t ro = (size_t)(bid + k * 1024) * 256 + (half << 7);
#pragma unroll
      for (int ct = 0; ct < 2; ++ct) {
        const int c0l = w * 32 + ct * 16 + quad * 4;
        float4 v;
        v.x = acc[kt][ct][0];
        v.y = acc[kt][ct][1];
        v.z = acc[kt][ct][2];
        v.w = acc[kt][ct][3];
        *(float4*)(out_slot + ro + c0l) = v;
        const uint2 ff = ffp[kt][ct];
        float4 f;
        f.x = v.x + bfbits2f(ff.x << 16);
        f.y = v.y + bfbits2f(ff.x & 0xffff0000u);
        f.z = v.z + bfbits2f(ff.y << 16);
        f.w = v.w + bfbits2f(ff.y & 0xffff0000u);
        *(float4*)(fused_slot + ro + c0l) = f;
      }
    }
  }
}

extern "C" void kernel_launch(void* const* d_in, const int* in_sizes, int n_in,
                              void* d_out, int out_size, void* d_ws, size_t ws_size,
                              hipStream_t stream) {
  const float* feature = (const float*)d_in[0];
  const float* rois = (const float*)d_in[1];
  const float* Ww = (const float*)d_in[2];
  const float* bw = (const float*)d_in[3];
  const float* Wf = (const float*)d_in[4];
  const float* bfv = (const float*)d_in[5];
  const float* Wpw = (const float*)d_in[6];
  const float* bpw = (const float*)d_in[7];

  unsigned short* wsWf = (unsigned short*)d_ws;       // 65536 bf16 (frag-major)
  unsigned short* wsWw = wsWf + 256 * 256;            // 65536 bf16 (frag-major)
  unsigned short* wsWpw = wsWw + 256 * 256;           // 16384 bf16 (frag-major)

  float* fused_slot = (float*)d_out;
  float* out_slot = fused_slot + (size_t)MM * 256;

  k_convert<<<40, 256, 0, stream>>>(Wf, Ww, Wpw, wsWf, wsWw, wsWpw);
  k1<<<MM / 64, 256, 0, stream>>>(rois, wsWf, wsWw, wsWpw, bfv, bw, bpw,
                                  out_slot);
  k2<<<2 * NN * FWBv * FWBv, 256, 0, stream>>>(feature, fused_slot, out_slot);
}

// Round 7
// 429.362 us; speedup vs baseline: 1.0027x; 1.0027x over previous
//
#include <hip/hip_runtime.h>

#define NN 4
#define CC 256
#define HH 128
#define FWBv 16
#define BLK 8
#define NBBOX 100
#define MM (NBBOX * NN * FWBv * FWBv)  // 102400

typedef __attribute__((ext_vector_type(8))) short bf16x8;
typedef __attribute__((ext_vector_type(4))) float f32x4;

__device__ __forceinline__ unsigned short f2bf(float x) {
  union { float f; unsigned int u; } v; v.f = x;
  unsigned int r = v.u + 0x7FFFu + ((v.u >> 16) & 1u);
  return (unsigned short)(r >> 16);
}

__device__ __forceinline__ float bfbits2f(unsigned int hi16) {
  union { float f; unsigned int u; } v; v.u = hi16;
  return v.f;
}

__device__ __forceinline__ unsigned int pk(float a, float b) {
  return (unsigned int)f2bf(a) | ((unsigned int)f2bf(b) << 16);
}

// ---------------- Kernel 0: weight fp32 -> bf16, FRAGMENT-MAJOR ----------------
// Wf/Ww: fragment f = (kc*16 + g)*64 + lane  (kc<8, g<16, lane<64)
//   holds W[g*16 + (lane&15)][kc*32 + (lane>>4)*8 + j], j=0..7  (16B per lane)
// Wpw:   fragment f = (kc*4 + g)*64 + lane   (kc<8, g<4)
__global__ __launch_bounds__(256) void k_convert(
    const float* __restrict__ Wf, const float* __restrict__ Ww,
    const float* __restrict__ Wpw,
    unsigned short* __restrict__ oWf, unsigned short* __restrict__ oWw,
    unsigned short* __restrict__ oWpw) {
  const int i = blockIdx.x * 256 + threadIdx.x;  // grid = 40 blocks -> i < 10240
  if (i < 8192) {
    const int lane = i & 63, g = (i >> 6) & 15, kc = i >> 10;
    const int row = g * 16 + (lane & 15);
    const int col0 = kc * 32 + (lane >> 4) * 8;
    {
      const float* s = Wf + (size_t)row * 256 + col0;
      const float4 a = *(const float4*)s, b = *(const float4*)(s + 4);
      *(uint4*)(oWf + (size_t)i * 8) =
          make_uint4(pk(a.x, a.y), pk(a.z, a.w), pk(b.x, b.y), pk(b.z, b.w));
    }
    {
      const float* s = Ww + (size_t)row * 256 + col0;
      const float4 a = *(const float4*)s, b = *(const float4*)(s + 4);
      *(uint4*)(oWw + (size_t)i * 8) =
          make_uint4(pk(a.x, a.y), pk(a.z, a.w), pk(b.x, b.y), pk(b.z, b.w));
    }
  } else {
    const int j = i - 8192;  // [0, 2048)
    const int lane = j & 63, g = (j >> 6) & 3, kc = j >> 8;
    const int row = g * 16 + (lane & 15);
    const int col0 = kc * 32 + (lane >> 4) * 8;
    const float* s = Wpw + (size_t)row * 256 + col0;
    const float4 a = *(const float4*)s, b = *(const float4*)(s + 4);
    *(uint4*)(oWpw + (size_t)j * 8) =
        make_uint4(pk(a.x, a.y), pk(a.z, a.w), pk(b.x, b.y), pk(b.z, b.w));
  }
}

// fragment load: one coalesced 1KB global_load_dwordx4 per wave
__device__ __forceinline__ bf16x8 ld_frag(const unsigned short* __restrict__ W,
                                          int frag, int lane) {
  return *(const bf16x8*)(W + (((size_t)frag * 64 + lane) << 3));
}

// One BK=32 compute step: weights already in regs; 4 ds_read (xs) + 16 MFMA.
__device__ __forceinline__ void bodyR(const bf16x8 aw[4],
                                      const unsigned short (*xsp)[264],
                                      int kcol, int lr, f32x4 acc[4][4]) {
  bf16x8 bx[4];
#pragma unroll
  for (int mt = 0; mt < 4; ++mt)
    bx[mt] = *(const bf16x8*)&xsp[mt * 16 + lr][kcol];
  __builtin_amdgcn_s_setprio(1);
#pragma unroll
  for (int mt = 0; mt < 4; ++mt)
#pragma unroll
    for (int nt = 0; nt < 4; ++nt)
      acc[mt][nt] = __builtin_amdgcn_mfma_f32_16x16x32_bf16(
          aw[nt], bx[mt], acc[mt][nt], 0, 0, 0);
  __builtin_amdgcn_s_setprio(0);
}

// ---------------- Kernel 1: feat_f, feat_w, point_weight ----------------
// R7: depth-2 weight prefetch (aw[3][4] rotation; fragments issued 2 chunks
// ahead; chunks 0+1 in flight under the X-stage). Layout/structure = R5:
//   bytes [0,128)   : pw bf16[64]      (pass C)
//   bytes [256,768) : feat_f bf16[256] (pass A)
__global__ __launch_bounds__(256, 3) void k1(
    const float* __restrict__ rois,
    const unsigned short* __restrict__ Wf,   // bf16 fragment-major [8192][8]
    const unsigned short* __restrict__ Ww,   // bf16 fragment-major [8192][8]
    const unsigned short* __restrict__ Wpw,  // bf16 fragment-major [2048][8]
    const float* __restrict__ bf_, const float* __restrict__ bw_,
    const float* __restrict__ bpw_,
    float* __restrict__ out_slot)
{
  __shared__ __align__(16) unsigned short xs[64][264];  // 33.8 KB, only LDS
  unsigned short* os = (unsigned short*)out_slot;
  const int t = threadIdx.x;
  const int lane = t & 63, w = t >> 6;
  const int lr = lane & 15, quad = lane >> 4;
  const int row_base = blockIdx.x * 64;
  const int w4 = w * 4;

  // prologue: chunks 0 AND 1 of Wf in flight during the X stage (depth 2)
  bf16x8 aw[3][4];
#pragma unroll
  for (int nt = 0; nt < 4; ++nt) aw[0][nt] = ld_frag(Wf, w4 + nt, lane);
#pragma unroll
  for (int nt = 0; nt < 4; ++nt) aw[1][nt] = ld_frag(Wf, 16 + w4 + nt, lane);

  // stage X: 64x256 fp32 -> bf16 LDS (coalesced float4 loads)
#pragma unroll
  for (int i = 0; i < 16; ++i) {
    const int elem = (i * 256 + t) * 4;
    const int r = elem >> 8, c = elem & 255;
    const float4 v = *(const float4*)(rois + (size_t)row_base * 256 + elem);
    *(uint2*)&xs[r][c] = make_uint2(pk(v.x, v.y), pk(v.z, v.w));
  }
  asm volatile("s_waitcnt lgkmcnt(0)" ::: "memory");
  __builtin_amdgcn_s_barrier();  // xs visible to all waves

  f32x4 acc[4][4];
#pragma unroll
  for (int mt = 0; mt < 4; ++mt)
#pragma unroll
    for (int nt = 0; nt < 4; ++nt) acc[mt][nt] = (f32x4){0.f, 0.f, 0.f, 0.f};

  // ---- pass A: feat_f = relu(x @ Wf^T + bf) ----
  // consume aw[kc%3]; prefetch chunk kc+2 into aw[(kc+2)%3]
  // (kc+2>7 rolls into pass-B chunks 0,1 of Ww)
#pragma unroll
  for (int kc = 0; kc < 8; ++kc) {
    const unsigned short* nsrc = (kc < 6) ? Wf : Ww;
    const int nkc = (kc < 6) ? kc + 2 : kc - 6;
#pragma unroll
    for (int nt = 0; nt < 4; ++nt)
      aw[(kc + 2) % 3][nt] = ld_frag(nsrc, nkc * 16 + w4 + nt, lane);
    bodyR(aw[kc % 3], xs, kc * 32 + quad * 8, lr, acc);
  }

  // epilogue A: feat_f = relu(acc+bias) -> bf16 into out_slot bytes [256,768)
#pragma unroll
  for (int nt = 0; nt < 4; ++nt) {
    const int col0 = w * 64 + nt * 16 + quad * 4;
    const float4 b4 = *(const float4*)(bf_ + col0);
#pragma unroll
    for (int mt = 0; mt < 4; ++mt) {
      float v0 = acc[mt][nt][0] + b4.x; v0 = v0 > 0.f ? v0 : 0.f;
      float v1 = acc[mt][nt][1] + b4.y; v1 = v1 > 0.f ? v1 : 0.f;
      float v2 = acc[mt][nt][2] + b4.z; v2 = v2 > 0.f ? v2 : 0.f;
      float v3 = acc[mt][nt][3] + b4.w; v3 = v3 > 0.f ? v3 : 0.f;
      *(uint2*)&os[(size_t)(row_base + mt * 16 + lr) * 512 + 128 + col0] =
          make_uint2(pk(v0, v1), pk(v2, v3));
      acc[mt][nt] = (f32x4){0.f, 0.f, 0.f, 0.f};  // reset for pass B
    }
  }

  // ---- pass B: feat_w = relu(x @ Ww^T + bw) ----
  // Ww chunk kc sits in aw[(kc+2)%3]; prefetch chunk kc+2 into aw[(kc+1)%3]
#pragma unroll
  for (int kc = 0; kc < 8; ++kc) {
    if (kc < 6) {
#pragma unroll
      for (int nt = 0; nt < 4; ++nt)
        aw[(kc + 1) % 3][nt] = ld_frag(Ww, (kc + 2) * 16 + w4 + nt, lane);
    }
    bodyR(aw[(kc + 2) % 3], xs, kc * 32 + quad * 8, lr, acc);
  }

  // prefetch ALL pass-C weights to regs (8KB/wave from L2, hides under epiB)
  bf16x8 apw[8];
#pragma unroll
  for (int idx = 0; idx < 8; ++idx)
    apw[idx] = ld_frag(Wpw, idx * 4 + w, lane);

  __builtin_amdgcn_s_barrier();  // ALL waves done reading xs (pass B)

  // epilogue B: feat_w = relu(acc + bias) -> bf16 back into xs
#pragma unroll
  for (int nt = 0; nt < 4; ++nt) {
    const int col0 = w * 64 + nt * 16 + quad * 4;
    const float4 b4 = *(const float4*)(bw_ + col0);
#pragma unroll
    for (int mt = 0; mt < 4; ++mt) {
      float v0 = acc[mt][nt][0] + b4.x; v0 = v0 > 0.f ? v0 : 0.f;
      float v1 = acc[mt][nt][1] + b4.y; v1 = v1 > 0.f ? v1 : 0.f;
      float v2 = acc[mt][nt][2] + b4.z; v2 = v2 > 0.f ? v2 : 0.f;
      float v3 = acc[mt][nt][3] + b4.w; v3 = v3 > 0.f ? v3 : 0.f;
      *(uint2*)&xs[mt * 16 + lr][col0] = make_uint2(pk(v0, v1), pk(v2, v3));
    }
  }
  asm volatile("s_waitcnt lgkmcnt(0)" ::: "memory");
  __builtin_amdgcn_s_barrier();  // new xs (feat_w) visible

  // ---- pass C: pw = feat_w @ Wpw^T + bpw, wave w -> cols [w*16, w*16+16) ----
  f32x4 acc2[4];
#pragma unroll
  for (int mt = 0; mt < 4; ++mt) acc2[mt] = (f32x4){0.f, 0.f, 0.f, 0.f};
#pragma unroll
  for (int idx = 0; idx < 8; ++idx) {  // idx = c*2+kt
    const int kcol = idx * 32 + quad * 8;
    __builtin_amdgcn_s_setprio(1);
#pragma unroll
    for (int mt = 0; mt < 4; ++mt) {
      const bf16x8 bx = *(const bf16x8*)&xs[mt * 16 + lr][kcol];
      acc2[mt] =
          __builtin_amdgcn_mfma_f32_16x16x32_bf16(apw[idx], bx, acc2[mt], 0, 0, 0);
    }
    __builtin_amdgcn_s_setprio(0);
  }
  // epilogue C: pw bf16 into out_slot bytes [0,128)
  {
    const int j0 = w * 16 + quad * 4;
    const float4 bj = *(const float4*)(bpw_ + j0);
#pragma unroll
    for (int mt = 0; mt < 4; ++mt) {
      const float v0 = acc2[mt][0] + bj.x, v1 = acc2[mt][1] + bj.y;
      const float v2 = acc2[mt][2] + bj.z, v3 = acc2[mt][3] + bj.w;
      *(uint2*)&os[(size_t)(row_base + mt * 16 + lr) * 512 + j0] =
          make_uint2(pk(v0, v1), pk(v2, v3));
    }
  }
}

// ---------------- Kernel 2: einsum + fused add ----------------
// (reverted to R5 exactly — best measured k2)
__global__ __launch_bounds__(512, 4) void k2(
    const float* __restrict__ feature,
    float* __restrict__ fused_slot,
    float* __restrict__ out_slot)
{
  __shared__ unsigned short fbuf[256][72];  // fb[c][j] bf16
  __shared__ unsigned short pwb[112][72];   // pw[k][j] bf16, rows 100..111 zero
  const int t = threadIdx.x;
  const int lane = t & 63, w = t >> 6;
  const int lr = lane & 15, quad = lane >> 4;
  const int d = blockIdx.x;                 // hardware block id
  const int bid = ((d & 7) << 7) | (d >> 3);  // XCD-chunked logical id
  const int n = bid >> 8, p = (bid >> 4) & 15, q = bid & 15;
  const unsigned short* os = (const unsigned short*)out_slot;

  // zero pad rows k=100..111 (12 rows x 72 ushort = 432 uints)
  if (t < 432) {
    const int r = 100 + t / 36, cw = t % 36;
    *(unsigned int*)&pwb[r][cw * 2] = 0u;
  }

  // stage feature block: (c,a) pairs, 8 contiguous floats each
  for (int pi = t; pi < 2048; pi += 512) {
    const int c = pi >> 3, a = pi & 7;
    const float* fp =
        feature + (((size_t)n * 256 + c) * 128 + p * 8 + a) * 128 + q * 8;
    const float4 v0 = *(const float4*)fp;
    const float4 v1 = *(const float4*)(fp + 4);
    *(uint4*)&fbuf[c][a * 8] =
        make_uint4(pk(v0.x, v0.y), pk(v0.z, v0.w), pk(v1.x, v1.y), pk(v1.z, v1.w));
  }

  // stage pw rows (already bf16): k = 0..99, 128B per row
  for (int pi = t; pi < 1600; pi += 512) {
    const int k = pi >> 4, ch = pi & 15;
    const uint2 v = *(const uint2*)&os[(size_t)(bid + k * 1024) * 512 + ch * 4];
    *(uint2*)&pwb[k][ch * 4] = v;
  }
  __syncthreads();

  // GEMM: mfma(fb_frag, pw_frag) -> D.row = channel, D.col = k
  f32x4 acc[7][2];
#pragma unroll
  for (int kt = 0; kt < 7; ++kt)
#pragma unroll
    for (int ct = 0; ct < 2; ++ct) acc[kt][ct] = (f32x4){0.f, 0.f, 0.f, 0.f};
#pragma unroll
  for (int kj = 0; kj < 2; ++kj) {
    const int kk = kj * 32 + quad * 8;
    bf16x8 fa[2];
#pragma unroll
    for (int ct = 0; ct < 2; ++ct)
      fa[ct] = *(const bf16x8*)&fbuf[w * 32 + ct * 16 + lr][kk];
    {  // half 1: kt 0..3
      bf16x8 pa[4];
#pragma unroll
      for (int kt = 0; kt < 4; ++kt)
        pa[kt] = *(const bf16x8*)&pwb[kt * 16 + lr][kk];
      __builtin_amdgcn_s_setprio(1);
#pragma unroll
      for (int kt = 0; kt < 4; ++kt)
#pragma unroll
        for (int ct = 0; ct < 2; ++ct)
          acc[kt][ct] = __builtin_amdgcn_mfma_f32_16x16x32_bf16(
              fa[ct], pa[kt], acc[kt][ct], 0, 0, 0);
      __builtin_amdgcn_s_setprio(0);
    }
    {  // half 2: kt 4..6
      bf16x8 pa[3];
#pragma unroll
      for (int kt = 0; kt < 3; ++kt)
        pa[kt] = *(const bf16x8*)&pwb[(kt + 4) * 16 + lr][kk];
      __builtin_amdgcn_s_setprio(1);
#pragma unroll
      for (int kt = 0; kt < 3; ++kt)
#pragma unroll
        for (int ct = 0; ct < 2; ++ct)
          acc[kt + 4][ct] = __builtin_amdgcn_mfma_f32_16x16x32_bf16(
              fa[ct], pa[kt], acc[kt + 4][ct], 0, 0, 0);
      __builtin_amdgcn_s_setprio(0);
    }
  }

  // feat_f bf16 prefetch (after GEMM: caps peak VGPR pressure)
  uint2 ffp[7][2];
#pragma unroll
  for (int kt = 0; kt < 7; ++kt) {
    const int k = kt * 16 + lr;
    if (k < 100) {
      const size_t ro = (size_t)(bid + k * 1024) * 512;
#pragma unroll
      for (int ct = 0; ct < 2; ++ct) {
        const int c0 = w * 32 + ct * 16 + quad * 4;
        ffp[kt][ct] = *(const uint2*)&os[ro + 128 + c0];
      }
    }
  }

  // fence: all feat_f/pw reads of this block complete before any row overwrite
  asm volatile("s_waitcnt vmcnt(0)" ::: "memory");
  __builtin_amdgcn_s_barrier();

  // epilogue: float4 stores; k = kt*16+lr, channels c0..c0+3
#pragma unroll
  for (int kt = 0; kt < 7; ++kt) {
    const int k = kt * 16 + lr;
    if (k < 100) {
      const size_t ro = (size_t)(bid + k * 1024) * 256;
#pragma unroll
      for (int ct = 0; ct < 2; ++ct) {
        const int c0 = w * 32 + ct * 16 + quad * 4;
        float4 v;
        v.x = acc[kt][ct][0];
        v.y = acc[kt][ct][1];
        v.z = acc[kt][ct][2];
        v.w = acc[kt][ct][3];
        *(float4*)(out_slot + ro + c0) = v;
        const uint2 ff = ffp[kt][ct];
        float4 f;
        f.x = v.x + bfbits2f(ff.x << 16);
        f.y = v.y + bfbits2f(ff.x & 0xffff0000u);
        f.z = v.z + bfbits2f(ff.y << 16);
        f.w = v.w + bfbits2f(ff.y & 0xffff0000u);
        *(float4*)(fused_slot + ro + c0) = f;
      }
    }
  }
}

extern "C" void kernel_launch(void* const* d_in, const int* in_sizes, int n_in,
                              void* d_out, int out_size, void* d_ws, size_t ws_size,
                              hipStream_t stream) {
  const float* feature = (const float*)d_in[0];
  const float* rois = (const float*)d_in[1];
  const float* Ww = (const float*)d_in[2];
  const float* bw = (const float*)d_in[3];
  const float* Wf = (const float*)d_in[4];
  const float* bfv = (const float*)d_in[5];
  const float* Wpw = (const float*)d_in[6];
  const float* bpw = (const float*)d_in[7];

  unsigned short* wsWf = (unsigned short*)d_ws;       // 65536 bf16 (frag-major)
  unsigned short* wsWw = wsWf + 256 * 256;            // 65536 bf16 (frag-major)
  unsigned short* wsWpw = wsWw + 256 * 256;           // 16384 bf16 (frag-major)

  float* fused_slot = (float*)d_out;
  float* out_slot = fused_slot + (size_t)MM * 256;

  k_convert<<<40, 256, 0, stream>>>(Wf, Ww, Wpw, wsWf, wsWw, wsWpw);
  k1<<<MM / 64, 256, 0, stream>>>(rois, wsWf, wsWw, wsWpw, bfv, bw, bpw,
                                  out_slot);
  k2<<<NN * FWBv * FWBv, 512, 0, stream>>>(feature, fused_slot, out_slot);
}

// Round 8
// 422.077 us; speedup vs baseline: 1.0200x; 1.0173x over previous
//
#include <hip/hip_runtime.h>

#define NN 4
#define CC 256
#define HH 128
#define FWBv 16
#define BLK 8
#define NBBOX 100
#define MM (NBBOX * NN * FWBv * FWBv)  // 102400

typedef __attribute__((ext_vector_type(8))) short bf16x8;
typedef __attribute__((ext_vector_type(4))) float f32x4;

__device__ __forceinline__ unsigned short f2bf(float x) {
  union { float f; unsigned int u; } v; v.f = x;
  unsigned int r = v.u + 0x7FFFu + ((v.u >> 16) & 1u);
  return (unsigned short)(r >> 16);
}

__device__ __forceinline__ float bfbits2f(unsigned int hi16) {
  union { float f; unsigned int u; } v; v.u = hi16;
  return v.f;
}

__device__ __forceinline__ unsigned int pk(float a, float b) {
  return (unsigned int)f2bf(a) | ((unsigned int)f2bf(b) << 16);
}

// ---------------- Kernel 0: weight fp32 -> bf16, FRAGMENT-MAJOR ----------------
// Wf/Ww: fragment f = (kc*16 + g)*64 + lane  (kc<8, g<16, lane<64)
//   holds W[g*16 + (lane&15)][kc*32 + (lane>>4)*8 + j], j=0..7  (16B per lane)
// Wpw:   fragment f = (kc*4 + g)*64 + lane   (kc<8, g<4)
__global__ __launch_bounds__(256) void k_convert(
    const float* __restrict__ Wf, const float* __restrict__ Ww,
    const float* __restrict__ Wpw,
    unsigned short* __restrict__ oWf, unsigned short* __restrict__ oWw,
    unsigned short* __restrict__ oWpw) {
  const int i = blockIdx.x * 256 + threadIdx.x;  // grid = 40 blocks -> i < 10240
  if (i < 8192) {
    const int lane = i & 63, g = (i >> 6) & 15, kc = i >> 10;
    const int row = g * 16 + (lane & 15);
    const int col0 = kc * 32 + (lane >> 4) * 8;
    {
      const float* s = Wf + (size_t)row * 256 + col0;
      const float4 a = *(const float4*)s, b = *(const float4*)(s + 4);
      *(uint4*)(oWf + (size_t)i * 8) =
          make_uint4(pk(a.x, a.y), pk(a.z, a.w), pk(b.x, b.y), pk(b.z, b.w));
    }
    {
      const float* s = Ww + (size_t)row * 256 + col0;
      const float4 a = *(const float4*)s, b = *(const float4*)(s + 4);
      *(uint4*)(oWw + (size_t)i * 8) =
          make_uint4(pk(a.x, a.y), pk(a.z, a.w), pk(b.x, b.y), pk(b.z, b.w));
    }
  } else {
    const int j = i - 8192;  // [0, 2048)
    const int lane = j & 63, g = (j >> 6) & 3, kc = j >> 8;
    const int row = g * 16 + (lane & 15);
    const int col0 = kc * 32 + (lane >> 4) * 8;
    const float* s = Wpw + (size_t)row * 256 + col0;
    const float4 a = *(const float4*)s, b = *(const float4*)(s + 4);
    *(uint4*)(oWpw + (size_t)j * 8) =
        make_uint4(pk(a.x, a.y), pk(a.z, a.w), pk(b.x, b.y), pk(b.z, b.w));
  }
}

// fragment load: one coalesced 1KB global_load_dwordx4 per wave
__device__ __forceinline__ bf16x8 ld_frag(const unsigned short* __restrict__ W,
                                          int frag, int lane) {
  return *(const bf16x8*)(W + (((size_t)frag * 64 + lane) << 3));
}

// One BK=32 compute step: weights already in regs; 4 ds_read (xs) + 16 MFMA.
__device__ __forceinline__ void bodyR(const bf16x8 aw[4],
                                      const unsigned short (*xsp)[264],
                                      int kcol, int lr, f32x4 acc[4][4]) {
  bf16x8 bx[4];
#pragma unroll
  for (int mt = 0; mt < 4; ++mt)
    bx[mt] = *(const bf16x8*)&xsp[mt * 16 + lr][kcol];
  __builtin_amdgcn_s_setprio(1);
#pragma unroll
  for (int mt = 0; mt < 4; ++mt)
#pragma unroll
    for (int nt = 0; nt < 4; ++nt)
      acc[mt][nt] = __builtin_amdgcn_mfma_f32_16x16x32_bf16(
          aw[nt], bx[mt], acc[mt][nt], 0, 0, 0);
  __builtin_amdgcn_s_setprio(0);
}

// ---------------- Kernel 1: feat_f, feat_w, point_weight ----------------
// grid = MM/64 blocks, 256 threads (4 waves), 3 blocks/CU (LDS 33.8KB,
// VGPR capped by __launch_bounds__(256,3)). Weights consumed directly from
// L2 via fragment-major coalesced reg loads (depth-1 prefetch; depth-2
// measured null in R7). Outputs packed bf16 into out_slot rows (1KB each):
//   bytes [0,128)   : pw bf16[64]      (pass C)
//   bytes [256,768) : feat_f bf16[256] (pass A)
__global__ __launch_bounds__(256, 3) void k1(
    const float* __restrict__ rois,
    const unsigned short* __restrict__ Wf,   // bf16 fragment-major [8192][8]
    const unsigned short* __restrict__ Ww,   // bf16 fragment-major [8192][8]
    const unsigned short* __restrict__ Wpw,  // bf16 fragment-major [2048][8]
    const float* __restrict__ bf_, const float* __restrict__ bw_,
    const float* __restrict__ bpw_,
    float* __restrict__ out_slot)
{
  __shared__ __align__(16) unsigned short xs[64][264];  // 33.8 KB, only LDS
  unsigned short* os = (unsigned short*)out_slot;
  const int t = threadIdx.x;
  const int lane = t & 63, w = t >> 6;
  const int lr = lane & 15, quad = lane >> 4;
  const int row_base = blockIdx.x * 64;
  const int w4 = w * 4;

  // preload pass-A chunk 0 weights (in flight during the X stage)
  bf16x8 aw[2][4];
#pragma unroll
  for (int nt = 0; nt < 4; ++nt) aw[0][nt] = ld_frag(Wf, w4 + nt, lane);

  // stage X: 64x256 fp32 -> bf16 LDS (coalesced float4 loads)
#pragma unroll
  for (int i = 0; i < 16; ++i) {
    const int elem = (i * 256 + t) * 4;
    const int r = elem >> 8, c = elem & 255;
    const float4 v = *(const float4*)(rois + (size_t)row_base * 256 + elem);
    *(uint2*)&xs[r][c] = make_uint2(pk(v.x, v.y), pk(v.z, v.w));
  }
  asm volatile("s_waitcnt lgkmcnt(0)" ::: "memory");
  __builtin_amdgcn_s_barrier();  // xs visible to all waves

  f32x4 acc[4][4];
#pragma unroll
  for (int mt = 0; mt < 4; ++mt)
#pragma unroll
    for (int nt = 0; nt < 4; ++nt) acc[mt][nt] = (f32x4){0.f, 0.f, 0.f, 0.f};

  // ---- pass A: feat_f = relu(x @ Wf^T + bf) ----
#pragma unroll
  for (int kc = 0; kc < 8; ++kc) {
    const unsigned short* nsrc = (kc < 7) ? Wf : Ww;  // tail prefetches pass B
    const int nkc = (kc < 7) ? kc + 1 : 0;
#pragma unroll
    for (int nt = 0; nt < 4; ++nt)
      aw[(kc + 1) & 1][nt] = ld_frag(nsrc, nkc * 16 + w4 + nt, lane);
    bodyR(aw[kc & 1], xs, kc * 32 + quad * 8, lr, acc);
  }

  // epilogue A: feat_f = relu(acc+bias) -> bf16 into out_slot bytes [256,768)
#pragma unroll
  for (int nt = 0; nt < 4; ++nt) {
    const int col0 = w * 64 + nt * 16 + quad * 4;
    const float4 b4 = *(const float4*)(bf_ + col0);
#pragma unroll
    for (int mt = 0; mt < 4; ++mt) {
      float v0 = acc[mt][nt][0] + b4.x; v0 = v0 > 0.f ? v0 : 0.f;
      float v1 = acc[mt][nt][1] + b4.y; v1 = v1 > 0.f ? v1 : 0.f;
      float v2 = acc[mt][nt][2] + b4.z; v2 = v2 > 0.f ? v2 : 0.f;
      float v3 = acc[mt][nt][3] + b4.w; v3 = v3 > 0.f ? v3 : 0.f;
      *(uint2*)&os[(size_t)(row_base + mt * 16 + lr) * 512 + 128 + col0] =
          make_uint2(pk(v0, v1), pk(v2, v3));
      acc[mt][nt] = (f32x4){0.f, 0.f, 0.f, 0.f};  // reset for pass B
    }
  }

  // ---- pass B: feat_w = relu(x @ Ww^T + bw) ----
#pragma unroll
  for (int kc = 0; kc < 8; ++kc) {
    if (kc < 7) {
#pragma unroll
      for (int nt = 0; nt < 4; ++nt)
        aw[(kc + 1) & 1][nt] = ld_frag(Ww, (kc + 1) * 16 + w4 + nt, lane);
    }
    bodyR(aw[kc & 1], xs, kc * 32 + quad * 8, lr, acc);
  }

  // prefetch ALL pass-C weights to regs (8KB/wave from L2, hides under epiB)
  bf16x8 apw[8];
#pragma unroll
  for (int idx = 0; idx < 8; ++idx)
    apw[idx] = ld_frag(Wpw, idx * 4 + w, lane);

  __builtin_amdgcn_s_barrier();  // ALL waves done reading xs (pass B)

  // epilogue B: feat_w = relu(acc + bias) -> bf16 back into xs
#pragma unroll
  for (int nt = 0; nt < 4; ++nt) {
    const int col0 = w * 64 + nt * 16 + quad * 4;
    const float4 b4 = *(const float4*)(bw_ + col0);
#pragma unroll
    for (int mt = 0; mt < 4; ++mt) {
      float v0 = acc[mt][nt][0] + b4.x; v0 = v0 > 0.f ? v0 : 0.f;
      float v1 = acc[mt][nt][1] + b4.y; v1 = v1 > 0.f ? v1 : 0.f;
      float v2 = acc[mt][nt][2] + b4.z; v2 = v2 > 0.f ? v2 : 0.f;
      float v3 = acc[mt][nt][3] + b4.w; v3 = v3 > 0.f ? v3 : 0.f;
      *(uint2*)&xs[mt * 16 + lr][col0] = make_uint2(pk(v0, v1), pk(v2, v3));
    }
  }
  asm volatile("s_waitcnt lgkmcnt(0)" ::: "memory");
  __builtin_amdgcn_s_barrier();  // new xs (feat_w) visible

  // ---- pass C: pw = feat_w @ Wpw^T + bpw, wave w -> cols [w*16, w*16+16) ----
  f32x4 acc2[4];
#pragma unroll
  for (int mt = 0; mt < 4; ++mt) acc2[mt] = (f32x4){0.f, 0.f, 0.f, 0.f};
#pragma unroll
  for (int idx = 0; idx < 8; ++idx) {  // idx = c*2+kt
    const int kcol = idx * 32 + quad * 8;
    __builtin_amdgcn_s_setprio(1);
#pragma unroll
    for (int mt = 0; mt < 4; ++mt) {
      const bf16x8 bx = *(const bf16x8*)&xs[mt * 16 + lr][kcol];
      acc2[mt] =
          __builtin_amdgcn_mfma_f32_16x16x32_bf16(apw[idx], bx, acc2[mt], 0, 0, 0);
    }
    __builtin_amdgcn_s_setprio(0);
  }
  // epilogue C: pw bf16 into out_slot bytes [0,128)
  {
    const int j0 = w * 16 + quad * 4;
    const float4 bj = *(const float4*)(bpw_ + j0);
#pragma unroll
    for (int mt = 0; mt < 4; ++mt) {
      const float v0 = acc2[mt][0] + bj.x, v1 = acc2[mt][1] + bj.y;
      const float v2 = acc2[mt][2] + bj.z, v3 = acc2[mt][3] + bj.w;
      *(uint2*)&os[(size_t)(row_base + mt * 16 + lr) * 512 + j0] =
          make_uint2(pk(v0, v1), pk(v2, v3));
    }
  }
}

// ---------------- Kernel 2: einsum + fused add ----------------
// grid = 1024 blocks, 512 threads (8 waves), XCD-chunked block swizzle (R4),
// VGPR<=128 via __launch_bounds__(512,4) (R5). Best measured config.
__global__ __launch_bounds__(512, 4) void k2(
    const float* __restrict__ feature,
    float* __restrict__ fused_slot,
    float* __restrict__ out_slot)
{
  __shared__ unsigned short fbuf[256][72];  // fb[c][j] bf16
  __shared__ unsigned short pwb[112][72];   // pw[k][j] bf16, rows 100..111 zero
  const int t = threadIdx.x;
  const int lane = t & 63, w = t >> 6;
  const int lr = lane & 15, quad = lane >> 4;
  const int d = blockIdx.x;                 // hardware block id
  const int bid = ((d & 7) << 7) | (d >> 3);  // XCD-chunked logical id
  const int n = bid >> 8, p = (bid >> 4) & 15, q = bid & 15;
  const unsigned short* os = (const unsigned short*)out_slot;

  // zero pad rows k=100..111 (12 rows x 72 ushort = 432 uints)
  if (t < 432) {
    const int r = 100 + t / 36, cw = t % 36;
    *(unsigned int*)&pwb[r][cw * 2] = 0u;
  }

  // stage feature block: (c,a) pairs, 8 contiguous floats each
  for (int pi = t; pi < 2048; pi += 512) {
    const int c = pi >> 3, a = pi & 7;
    const float* fp =
        feature + (((size_t)n * 256 + c) * 128 + p * 8 + a) * 128 + q * 8;
    const float4 v0 = *(const float4*)fp;
    const float4 v1 = *(const float4*)(fp + 4);
    *(uint4*)&fbuf[c][a * 8] =
        make_uint4(pk(v0.x, v0.y), pk(v0.z, v0.w), pk(v1.x, v1.y), pk(v1.z, v1.w));
  }

  // stage pw rows (already bf16): k = 0..99, 128B per row
  for (int pi = t; pi < 1600; pi += 512) {
    const int k = pi >> 4, ch = pi & 15;
    const uint2 v = *(const uint2*)&os[(size_t)(bid + k * 1024) * 512 + ch * 4];
    *(uint2*)&pwb[k][ch * 4] = v;
  }
  __syncthreads();

  // GEMM: mfma(fb_frag, pw_frag) -> D.row = channel, D.col = k
  f32x4 acc[7][2];
#pragma unroll
  for (int kt = 0; kt < 7; ++kt)
#pragma unroll
    for (int ct = 0; ct < 2; ++ct) acc[kt][ct] = (f32x4){0.f, 0.f, 0.f, 0.f};
#pragma unroll
  for (int kj = 0; kj < 2; ++kj) {
    const int kk = kj * 32 + quad * 8;
    bf16x8 fa[2];
#pragma unroll
    for (int ct = 0; ct < 2; ++ct)
      fa[ct] = *(const bf16x8*)&fbuf[w * 32 + ct * 16 + lr][kk];
    {  // half 1: kt 0..3
      bf16x8 pa[4];
#pragma unroll
      for (int kt = 0; kt < 4; ++kt)
        pa[kt] = *(const bf16x8*)&pwb[kt * 16 + lr][kk];
      __builtin_amdgcn_s_setprio(1);
#pragma unroll
      for (int kt = 0; kt < 4; ++kt)
#pragma unroll
        for (int ct = 0; ct < 2; ++ct)
          acc[kt][ct] = __builtin_amdgcn_mfma_f32_16x16x32_bf16(
              fa[ct], pa[kt], acc[kt][ct], 0, 0, 0);
      __builtin_amdgcn_s_setprio(0);
    }
    {  // half 2: kt 4..6
      bf16x8 pa[3];
#pragma unroll
      for (int kt = 0; kt < 3; ++kt)
        pa[kt] = *(const bf16x8*)&pwb[(kt + 4) * 16 + lr][kk];
      __builtin_amdgcn_s_setprio(1);
#pragma unroll
      for (int kt = 0; kt < 3; ++kt)
#pragma unroll
        for (int ct = 0; ct < 2; ++ct)
          acc[kt + 4][ct] = __builtin_amdgcn_mfma_f32_16x16x32_bf16(
              fa[ct], pa[kt], acc[kt + 4][ct], 0, 0, 0);
      __builtin_amdgcn_s_setprio(0);
    }
  }

  // feat_f bf16 prefetch (after GEMM: caps peak VGPR pressure)
  uint2 ffp[7][2];
#pragma unroll
  for (int kt = 0; kt < 7; ++kt) {
    const int k = kt * 16 + lr;
    if (k < 100) {
      const size_t ro = (size_t)(bid + k * 1024) * 512;
#pragma unroll
      for (int ct = 0; ct < 2; ++ct) {
        const int c0 = w * 32 + ct * 16 + quad * 4;
        ffp[kt][ct] = *(const uint2*)&os[ro + 128 + c0];
      }
    }
  }

  // fence: all feat_f/pw reads of this block complete before any row overwrite
  asm volatile("s_waitcnt vmcnt(0)" ::: "memory");
  __builtin_amdgcn_s_barrier();

  // epilogue: float4 stores; k = kt*16+lr, channels c0..c0+3
#pragma unroll
  for (int kt = 0; kt < 7; ++kt) {
    const int k = kt * 16 + lr;
    if (k < 100) {
      const size_t ro = (size_t)(bid + k * 1024) * 256;
#pragma unroll
      for (int ct = 0; ct < 2; ++ct) {
        const int c0 = w * 32 + ct * 16 + quad * 4;
        float4 v;
        v.x = acc[kt][ct][0];
        v.y = acc[kt][ct][1];
        v.z = acc[kt][ct][2];
        v.w = acc[kt][ct][3];
        *(float4*)(out_slot + ro + c0) = v;
        const uint2 ff = ffp[kt][ct];
        float4 f;
        f.x = v.x + bfbits2f(ff.x << 16);
        f.y = v.y + bfbits2f(ff.x & 0xffff0000u);
        f.z = v.z + bfbits2f(ff.y << 16);
        f.w = v.w + bfbits2f(ff.y & 0xffff0000u);
        *(float4*)(fused_slot + ro + c0) = f;
      }
    }
  }
}

extern "C" void kernel_launch(void* const* d_in, const int* in_sizes, int n_in,
                              void* d_out, int out_size, void* d_ws, size_t ws_size,
                              hipStream_t stream) {
  const float* feature = (const float*)d_in[0];
  const float* rois = (const float*)d_in[1];
  const float* Ww = (const float*)d_in[2];
  const float* bw = (const float*)d_in[3];
  const float* Wf = (const float*)d_in[4];
  const float* bfv = (const float*)d_in[5];
  const float* Wpw = (const float*)d_in[6];
  const float* bpw = (const float*)d_in[7];

  unsigned short* wsWf = (unsigned short*)d_ws;       // 65536 bf16 (frag-major)
  unsigned short* wsWw = wsWf + 256 * 256;            // 65536 bf16 (frag-major)
  unsigned short* wsWpw = wsWw + 256 * 256;           // 16384 bf16 (frag-major)

  float* fused_slot = (float*)d_out;
  float* out_slot = fused_slot + (size_t)MM * 256;

  k_convert<<<40, 256, 0, stream>>>(Wf, Ww, Wpw, wsWf, wsWw, wsWpw);
  k1<<<MM / 64, 256, 0, stream>>>(rois, wsWf, wsWw, wsWpw, bfv, bw, bpw,
                                  out_slot);
  k2<<<NN * FWBv * FWBv, 512, 0, stream>>>(feature, fused_slot, out_slot);
}